// Round 2
// baseline (1202.959 us; speedup 1.0000x reference)
//
#include <hip/hip_runtime.h>
#include <hip/hip_bf16.h>
#include <stdint.h>

// Problem constants (from reference): E,B,S,D,F = 8,8,2048,1024,4096.
#define E_ 8
#define B_ 8
#define S_ 2048
#define D_ 1024
#define F_ 4096

typedef short short8 __attribute__((ext_vector_type(8)));   // 8 bf16 = 4 VGPRs
typedef float f32x4  __attribute__((ext_vector_type(4)));
typedef unsigned short u16;

union U16x8 { uint4 v; u16 s[8]; };
union U16x4 { uint2 v; u16 s[4]; };

__device__ __forceinline__ float gelu_exact(float x) {
    // jax.nn.gelu(approximate=False) = x * 0.5 * (1 + erf(x/sqrt(2)))
    return 0.5f * x * (1.0f + erff(x * 0.70710678118654752f));
}

// Load 8 consecutive elements as bf16 bits, from either an f32 or bf16 buffer.
template<bool F32>
__device__ __forceinline__ U16x8 load8(const void* p, size_t elem_off) {
    U16x8 r;
    if constexpr (F32) {
        const float* f = (const float*)p + elem_off;
        const float4 v0 = *(const float4*)f;
        const float4 v1 = *(const float4*)(f + 4);
        float vv[8] = {v0.x, v0.y, v0.z, v0.w, v1.x, v1.y, v1.z, v1.w};
#pragma unroll
        for (int i = 0; i < 8; ++i) {
            __hip_bfloat16 b = __float2bfloat16(vv[i]);
            r.s[i] = *(const u16*)&b;
        }
    } else {
        r.v = *(const uint4*)((const u16*)p + elem_off);
    }
    return r;
}

template<bool F32>
__device__ __forceinline__ void store_out(void* Y, size_t idx, float v) {
    if constexpr (F32) {
        ((float*)Y)[idx] = v;
    } else {
        __hip_bfloat16 b = __float2bfloat16(v);
        ((u16*)Y)[idx] = *(const u16*)&b;
    }
}

// ---------------------------------------------------------------------------
// Dtype detector: even-indexed u16s of a bf16 tensor are bf16 normals
// (exponent ~[100,140]); of an f32 tensor they are low-mantissa fragments
// (exponent uniform-random, ~16% in range). Majority vote over 1024 samples.
// flag = 1 -> f32 buffers, flag = 0 -> bf16 buffers.
// ---------------------------------------------------------------------------
__global__ void detect_dtype(const u16* __restrict__ X, int* __restrict__ flag) {
    __shared__ int cnt;
    if (threadIdx.x == 0) cnt = 0;
    __syncthreads();
    int good = 0;
#pragma unroll
    for (int i = 0; i < 4; ++i) {
        const unsigned v = X[(threadIdx.x * 4 + i) * 2];   // even indices < 2048
        const unsigned e = (v >> 7) & 0xFF;
        good += (e >= 100 && e <= 140) ? 1 : 0;
    }
    atomicAdd(&cnt, good);
    __syncthreads();
    if (threadIdx.x == 0) *flag = (cnt < 512) ? 1 : 0;
}

// ---------------------------------------------------------------------------
// Kernel 1 body: H[b,s,f] = gelu(X@W1) * (X@W3), expert per batch row.
// Tile BM=128 x BN=64 x BK=64, 4 waves 2x2; 16x16x32 bf16 MFMA.
// LDS rows padded to 72 elems (16B-aligned, conflict-balanced b128 reads).
// Weights are k-major [d][f] -> staged with a 4x8 register transpose.
// ---------------------------------------------------------------------------
template<bool F32>
__device__ __forceinline__ void gateup_body(
        const void* __restrict__ X, const void* __restrict__ W1,
        const void* __restrict__ W3, const int* __restrict__ langs,
        u16* __restrict__ H, int s_off, int schunk,
        u16* sX, u16* sW1, u16* sW3)
{
    const int f0 = blockIdx.x * 64;
    const int sl = blockIdx.y * 128;
    const int b  = blockIdx.z;
    const int e  = (langs[b] - 4) & 7;

    const int t    = threadIdx.x;
    const int lane = t & 63;
    const int w    = t >> 6;
    const int wr   = w >> 1, wc = w & 1;
    const int lm   = lane & 15;
    const int lq   = lane >> 4;

    // W staging: 256 threads = 2 matrices x 16 k-blocks(4 rows) x 8 f-blocks(8 cols)
    const int wsel = t >> 7;
    const int idx  = t & 127;
    const int nb   = idx & 7;
    const int kb   = idx >> 3;
    const int wn   = nb * 8;
    const int wk   = kb * 4;
    const void* Wsrc  = wsel ? W3 : W1;
    u16*        sWdst = wsel ? sW3 : sW1;

    f32x4 acc1[4][2], acc2[4][2];
#pragma unroll
    for (int i = 0; i < 4; ++i)
#pragma unroll
        for (int j = 0; j < 2; ++j) {
            acc1[i][j] = (f32x4){0.f, 0.f, 0.f, 0.f};
            acc2[i][j] = (f32x4){0.f, 0.f, 0.f, 0.f};
        }

    const size_t xbase = ((size_t)b * S_ + s_off + sl) * D_;
    const size_t wbase = (size_t)e * D_ * F_ + f0;

    for (int kt = 0; kt < D_ / 64; ++kt) {
        const int k0 = kt * 64;
        U16x8 xr[4];
#pragma unroll
        for (int i = 0; i < 4; ++i) {
            const int ch  = t + i * 256;
            const int row = ch >> 3;
            const int kk  = (ch & 7) * 8;
            xr[i] = load8<F32>(X, xbase + (size_t)row * D_ + k0 + kk);
        }
        U16x8 rr[4];
#pragma unroll
        for (int r = 0; r < 4; ++r)
            rr[r] = load8<F32>(Wsrc, wbase + (size_t)(k0 + wk + r) * F_ + wn);

        __syncthreads();   // previous iteration's LDS readers done
#pragma unroll
        for (int i = 0; i < 4; ++i) {
            const int ch  = t + i * 256;
            const int row = ch >> 3;
            const int kk  = (ch & 7) * 8;
            *(uint4*)(sX + row * 72 + kk) = xr[i].v;
        }
#pragma unroll
        for (int j = 0; j < 8; ++j) {
            U16x4 o;
            o.s[0] = rr[0].s[j]; o.s[1] = rr[1].s[j];
            o.s[2] = rr[2].s[j]; o.s[3] = rr[3].s[j];
            *(uint2*)(sWdst + (wn + j) * 72 + wk) = o.v;
        }
        __syncthreads();

#pragma unroll
        for (int kk = 0; kk < 64; kk += 32) {
            short8 a[4], b1[2], b3[2];
#pragma unroll
            for (int i = 0; i < 4; ++i)
                a[i] = *(const short8*)(sX + (wr * 64 + i * 16 + lm) * 72 + kk + lq * 8);
#pragma unroll
            for (int j = 0; j < 2; ++j) {
                b1[j] = *(const short8*)(sW1 + (wc * 32 + j * 16 + lm) * 72 + kk + lq * 8);
                b3[j] = *(const short8*)(sW3 + (wc * 32 + j * 16 + lm) * 72 + kk + lq * 8);
            }
#pragma unroll
            for (int i = 0; i < 4; ++i)
#pragma unroll
                for (int j = 0; j < 2; ++j) {
                    acc1[i][j] = __builtin_amdgcn_mfma_f32_16x16x32_bf16(a[i], b1[j], acc1[i][j], 0, 0, 0);
                    acc2[i][j] = __builtin_amdgcn_mfma_f32_16x16x32_bf16(a[i], b3[j], acc2[i][j], 0, 0, 0);
                }
        }
    }

    // C/D layout: col = lane&15 (n, from 2nd operand), row = (lane>>4)*4+reg (m)
#pragma unroll
    for (int i = 0; i < 4; ++i)
#pragma unroll
        for (int j = 0; j < 2; ++j)
#pragma unroll
            for (int r = 0; r < 4; ++r) {
                const int row = wr * 64 + i * 16 + lq * 4 + r;
                const int col = wc * 32 + j * 16 + lm;
                const float hv = gelu_exact(acc1[i][j][r]) * acc2[i][j][r];
                __hip_bfloat16 hb = __float2bfloat16(hv);
                H[((size_t)b * schunk + sl + row) * F_ + f0 + col] = *(const u16*)&hb;
            }
}

__global__ __launch_bounds__(256, 2)
void gateup_kernel(const void* __restrict__ X, const void* __restrict__ W1,
                   const void* __restrict__ W3, const int* __restrict__ langs,
                   u16* __restrict__ H, int s_off, int schunk,
                   const int* __restrict__ flag)
{
    __shared__ u16 sX [128 * 72];
    __shared__ u16 sW1[ 64 * 72];
    __shared__ u16 sW3[ 64 * 72];
    if (*flag)
        gateup_body<true >(X, W1, W3, langs, H, s_off, schunk, sX, sW1, sW3);
    else
        gateup_body<false>(X, W1, W3, langs, H, s_off, schunk, sX, sW1, sW3);
}

// ---------------------------------------------------------------------------
// Kernel 2 body: Y[b,s,d] = (H @ W2) * rw.  Tile 128x128 x BK=64.
// H (bf16, k-contiguous) is the A operand; W2 is k-major -> transpose staging.
// rw = 1 here (cnt per row is 0 or 1 -> weight 1 either way).
// ---------------------------------------------------------------------------
template<bool F32>
__device__ __forceinline__ void down_body(
        const u16* __restrict__ Hm, const void* __restrict__ W2,
        const int* __restrict__ langs, void* __restrict__ Y,
        int s_off, int schunk, u16* sH, u16* sW)
{
    const int d0 = blockIdx.x * 128;
    const int sl = blockIdx.y * 128;
    const int b  = blockIdx.z;
    const int e  = (langs[b] - 4) & 7;

    const int t    = threadIdx.x;
    const int lane = t & 63;
    const int w    = t >> 6;
    const int wr   = w >> 1, wc = w & 1;
    const int lm   = lane & 15;
    const int lq   = lane >> 4;

    const int nb = t & 15;
    const int kb = t >> 4;
    const int wn = nb * 8;
    const int wk = kb * 4;

    f32x4 acc[4][4];
#pragma unroll
    for (int i = 0; i < 4; ++i)
#pragma unroll
        for (int j = 0; j < 4; ++j) acc[i][j] = (f32x4){0.f, 0.f, 0.f, 0.f};

    const size_t hbase = ((size_t)b * schunk + sl) * F_;
    const size_t wbase = (size_t)e * F_ * D_ + d0;

    for (int kt = 0; kt < F_ / 64; ++kt) {
        const int k0 = kt * 64;
        U16x8 hr[4];
#pragma unroll
        for (int i = 0; i < 4; ++i) {
            const int ch  = t + i * 256;
            const int row = ch >> 3;
            const int kk  = (ch & 7) * 8;
            hr[i] = load8<false>(Hm, hbase + (size_t)row * F_ + k0 + kk);
        }
        U16x8 rr[4];
#pragma unroll
        for (int r = 0; r < 4; ++r)
            rr[r] = load8<F32>(W2, wbase + (size_t)(k0 + wk + r) * D_ + wn);

        __syncthreads();
#pragma unroll
        for (int i = 0; i < 4; ++i) {
            const int ch  = t + i * 256;
            const int row = ch >> 3;
            const int kk  = (ch & 7) * 8;
            *(uint4*)(sH + row * 72 + kk) = hr[i].v;
        }
#pragma unroll
        for (int j = 0; j < 8; ++j) {
            U16x4 o;
            o.s[0] = rr[0].s[j]; o.s[1] = rr[1].s[j];
            o.s[2] = rr[2].s[j]; o.s[3] = rr[3].s[j];
            *(uint2*)(sW + (wn + j) * 72 + wk) = o.v;
        }
        __syncthreads();

#pragma unroll
        for (int kk = 0; kk < 64; kk += 32) {
            short8 a[4], bb[4];
#pragma unroll
            for (int i = 0; i < 4; ++i)
                a[i] = *(const short8*)(sH + (wr * 64 + i * 16 + lm) * 72 + kk + lq * 8);
#pragma unroll
            for (int j = 0; j < 4; ++j)
                bb[j] = *(const short8*)(sW + (wc * 64 + j * 16 + lm) * 72 + kk + lq * 8);
#pragma unroll
            for (int i = 0; i < 4; ++i)
#pragma unroll
                for (int j = 0; j < 4; ++j)
                    acc[i][j] = __builtin_amdgcn_mfma_f32_16x16x32_bf16(a[i], bb[j], acc[i][j], 0, 0, 0);
        }
    }

#pragma unroll
    for (int i = 0; i < 4; ++i)
#pragma unroll
        for (int j = 0; j < 4; ++j)
#pragma unroll
            for (int r = 0; r < 4; ++r) {
                const int row = wr * 64 + i * 16 + lq * 4 + r;
                const int col = wc * 64 + j * 16 + lm;
                store_out<F32>(Y, ((size_t)b * S_ + s_off + sl + row) * D_ + d0 + col,
                               acc[i][j][r]);
            }
}

__global__ __launch_bounds__(256, 2)
void down_kernel(const u16* __restrict__ Hm, const void* __restrict__ W2,
                 const int* __restrict__ langs, void* __restrict__ Y,
                 int s_off, int schunk, const int* __restrict__ flag)
{
    __shared__ u16 sH[128 * 72];
    __shared__ u16 sW[128 * 72];
    if (*flag)
        down_body<true >(Hm, W2, langs, Y, s_off, schunk, sH, sW);
    else
        down_body<false>(Hm, W2, langs, Y, s_off, schunk, sH, sW);
}

extern "C" void kernel_launch(void* const* d_in, const int* in_sizes, int n_in,
                              void* d_out, int out_size, void* d_ws, size_t ws_size,
                              hipStream_t stream) {
    // setup_inputs dict order: hidden_states, w1, w2, w3, langs  (w2 BEFORE w3!)
    const void* X  = d_in[0];
    const void* W1 = d_in[1];
    const void* W2 = d_in[2];
    const void* W3 = d_in[3];
    const int* langs = (const int*)d_in[4];

    int* flag = (int*)d_ws;                          // dtype flag at ws[0]
    u16* H    = (u16*)((char*)d_ws + 256);           // H region after flag

    detect_dtype<<<1, 256, 0, stream>>>((const u16*)X, flag);

    // Chunk S if the workspace can't hold full H (full H = 128 MiB).
    const size_t avail = (ws_size > 256) ? (ws_size - 256) : 0;
    const size_t slab  = (size_t)B_ * F_ * 2 * 128;  // 8 MiB per 128-row slab
    int nslabs = (int)(avail / slab);
    if (nslabs < 1)  nslabs = 1;                     // best effort
    if (nslabs > S_ / 128) nslabs = S_ / 128;
    const int SCH = nslabs * 128;

    for (int s0 = 0; s0 < S_; s0 += SCH) {
        const int rows = (S_ - s0 < SCH) ? (S_ - s0) : SCH;
        dim3 g1(F_ / 64, rows / 128, B_);
        gateup_kernel<<<g1, 256, 0, stream>>>(X, W1, W3, langs, H, s0, SCH, flag);
        dim3 g2(D_ / 128, rows / 128, B_);
        down_kernel<<<g2, 256, 0, stream>>>(H, W2, langs, d_out, s0, SCH, flag);
    }
}

// Round 3
// 876.858 us; speedup vs baseline: 1.3719x; 1.3719x over previous
//
#include <hip/hip_runtime.h>
#include <hip/hip_bf16.h>
#include <stdint.h>

// Problem constants: E,B,S,D,F = 8,8,2048,1024,4096. Inputs/outputs are f32
// (proven R2: flag-branch passed + FETCH_SIZE matches f32 traffic).
#define E_ 8
#define B_ 8
#define S_ 2048
#define D_ 1024
#define F_ 4096

typedef short short8 __attribute__((ext_vector_type(8)));   // 8 bf16 = 4 VGPRs
typedef float f32x4  __attribute__((ext_vector_type(4)));
typedef unsigned short u16;

union U16x8 { uint4 v; u16 s[8]; };
union U16x4 { uint2 v; u16 s[4]; };

__device__ __forceinline__ float gelu_exact(float x) {
    return 0.5f * x * (1.0f + erff(x * 0.70710678118654752f));
}
__device__ __forceinline__ u16 f2b(float v) {
    __hip_bfloat16 b = __float2bfloat16(v);
    return *(const u16*)&b;
}

// Async global->LDS, 16 B per lane. LDS dest = wave-uniform base + lane*16.
__device__ __forceinline__ void gload_lds16(const u16* g, u16* l) {
    __builtin_amdgcn_global_load_lds(
        (const __attribute__((address_space(1))) uint32_t*)g,
        (__attribute__((address_space(3))) uint32_t*)l, 16, 0, 0);
}

// ===========================================================================
// Prep kernels (one-time, memory-bound)
// ===========================================================================
__global__ void convert_x(const float* __restrict__ X, u16* __restrict__ Xb) {
    const size_t i = ((size_t)blockIdx.x * 256 + threadIdx.x) * 8;
    const float4 v0 = *(const float4*)(X + i);
    const float4 v1 = *(const float4*)(X + i + 4);
    U16x8 o;
    o.s[0] = f2b(v0.x); o.s[1] = f2b(v0.y); o.s[2] = f2b(v0.z); o.s[3] = f2b(v0.w);
    o.s[4] = f2b(v1.x); o.s[5] = f2b(v1.y); o.s[6] = f2b(v1.z); o.s[7] = f2b(v1.w);
    *(uint4*)(Xb + i) = o.v;
}

// src f32 [z][R][C] -> dst bf16 [z][C][R]  (64x64 tiles)
__global__ void transpose_w(const float* __restrict__ src, u16* __restrict__ dst,
                            int R, int C) {
    __shared__ u16 tile[64 * 72];
    const int c0 = blockIdx.x * 64;
    const int r0 = blockIdx.y * 64;
    const size_t base = (size_t)blockIdx.z * R * C;
    const int t  = threadIdx.x;
    const int rr = t >> 4;            // 0..15
    const int cc = (t & 15) * 4;      // 0..60
#pragma unroll
    for (int p = 0; p < 4; ++p) {
        const int r = rr + p * 16;
        const float4 v = *(const float4*)(src + base + (size_t)(r0 + r) * C + c0 + cc);
        tile[(cc + 0) * 72 + r] = f2b(v.x);
        tile[(cc + 1) * 72 + r] = f2b(v.y);
        tile[(cc + 2) * 72 + r] = f2b(v.z);
        tile[(cc + 3) * 72 + r] = f2b(v.w);
    }
    __syncthreads();
    const int cn = t >> 2;            // 0..63 (dst row within tile)
    const int ch = (t & 3) * 4;       // 0..12
#pragma unroll
    for (int p = 0; p < 4; ++p) {
        const int rch = ch + p * 16;  // 0..60
        *(uint2*)(dst + base + (size_t)(c0 + cn) * R + r0 + rch) =
            *(const uint2*)(tile + cn * 72 + rch);
    }
}

// ===========================================================================
// Fast-path GEMM 1: H = gelu(Xb@W1) * (Xb@W3), bf16 in, bf16 out.
// Xb [B][S][D]; W1t/W3t [E][F][D] (k-contiguous). Tile 128x(64+64), BK=64.
// LDS unpadded 64-elem rows with XOR granule swizzle g = r*8 + (c ^ (r&7)):
// staging permutes lane gptrs (global_load_lds needs contiguous LDS), reads
// land 8 lanes per 4-bank quad = conflict-floor ds_read_b128.
// ===========================================================================
__global__ __launch_bounds__(256, 2)
void gateup_v2(const u16* __restrict__ Xb, const u16* __restrict__ W1t,
               const u16* __restrict__ W3t, const int* __restrict__ langs,
               u16* __restrict__ H)
{
    __shared__ u16 sX [128 * 64];
    __shared__ u16 sW1[ 64 * 64];
    __shared__ u16 sW3[ 64 * 64];

    const int f0 = blockIdx.x * 64;
    const int s0 = blockIdx.y * 128;
    const int b  = blockIdx.z;
    const int e  = (langs[b] - 4) & 7;

    const int t    = threadIdx.x;
    const int lane = t & 63;
    const int w    = t >> 6;
    const int wr   = w >> 1, wc = w & 1;
    const int lm   = lane & 15;
    const int lq   = lane >> 4;
    const int lr   = lane >> 3;           // 0..7: row within 8-row staging group
    const int lcg  = (lane & 7) ^ lr;     // swizzled source col-granule
    const int hsw  = lm & 7;              // read-side swizzle key (= r&7)

    f32x4 acc1[4][2], acc2[4][2];
#pragma unroll
    for (int i = 0; i < 4; ++i)
#pragma unroll
        for (int j = 0; j < 2; ++j) {
            acc1[i][j] = (f32x4){0.f, 0.f, 0.f, 0.f};
            acc2[i][j] = (f32x4){0.f, 0.f, 0.f, 0.f};
        }

    const size_t xbase = ((size_t)b * S_ + s0) * D_;
    const size_t wbase = ((size_t)e * F_ + f0) * D_;
    const u16* xg  = Xb  + xbase + (size_t)(w * 32 + lr) * D_ + lcg * 8;
    const u16* w1g = W1t + wbase + (size_t)(w * 16 + lr) * D_ + lcg * 8;
    const u16* w3g = W3t + wbase + (size_t)(w * 16 + lr) * D_ + lcg * 8;

    for (int kt = 0; kt < D_ / 64; ++kt) {
        const int k0 = kt * 64;
        __syncthreads();   // prev iteration's ds_reads done
#pragma unroll
        for (int i = 0; i < 4; ++i)
            gload_lds16(xg + (size_t)i * 8 * D_ + k0, sX + (w * 32 + i * 8) * 64);
#pragma unroll
        for (int i = 0; i < 2; ++i) {
            gload_lds16(w1g + (size_t)i * 8 * D_ + k0, sW1 + (w * 16 + i * 8) * 64);
            gload_lds16(w3g + (size_t)i * 8 * D_ + k0, sW3 + (w * 16 + i * 8) * 64);
        }
        __syncthreads();   // compiler drains vmcnt before barrier

#pragma unroll
        for (int kk = 0; kk < 64; kk += 32) {
            const int cgb = kk >> 3;      // 0 or 4
            short8 a[4], b1[2], b3[2];
#pragma unroll
            for (int i = 0; i < 4; ++i) {
                const int r = wr * 64 + i * 16 + lm;     // r&7 == hsw
                a[i] = *(const short8*)(sX + r * 64 + (((cgb + lq) ^ hsw) << 3));
            }
#pragma unroll
            for (int j = 0; j < 2; ++j) {
                const int n = wc * 32 + j * 16 + lm;     // n&7 == hsw
                b1[j] = *(const short8*)(sW1 + n * 64 + (((cgb + lq) ^ hsw) << 3));
                b3[j] = *(const short8*)(sW3 + n * 64 + (((cgb + lq) ^ hsw) << 3));
            }
#pragma unroll
            for (int i = 0; i < 4; ++i)
#pragma unroll
                for (int j = 0; j < 2; ++j) {
                    acc1[i][j] = __builtin_amdgcn_mfma_f32_16x16x32_bf16(a[i], b1[j], acc1[i][j], 0, 0, 0);
                    acc2[i][j] = __builtin_amdgcn_mfma_f32_16x16x32_bf16(a[i], b3[j], acc2[i][j], 0, 0, 0);
                }
        }
    }

    // C/D: col = lane&15, row = (lane>>4)*4 + reg
#pragma unroll
    for (int i = 0; i < 4; ++i)
#pragma unroll
        for (int j = 0; j < 2; ++j)
#pragma unroll
            for (int r = 0; r < 4; ++r) {
                const int row = wr * 64 + i * 16 + lq * 4 + r;
                const int col = wc * 32 + j * 16 + lm;
                const float hv = gelu_exact(acc1[i][j][r]) * acc2[i][j][r];
                H[((size_t)b * S_ + s0 + row) * F_ + f0 + col] = f2b(hv);
            }
}

// ===========================================================================
// Fast-path GEMM 2: Y = H @ W2 (rw == 1).  H [B][S][F] bf16; W2t [E][D][F].
// Tile 128x128, BK=64, same swizzled global_load_lds structure.
// ===========================================================================
__global__ __launch_bounds__(256, 2)
void down_v2(const u16* __restrict__ H, const u16* __restrict__ W2t,
             const int* __restrict__ langs, float* __restrict__ Y)
{
    __shared__ u16 sH[128 * 64];
    __shared__ u16 sW[128 * 64];

    const int d0 = blockIdx.x * 128;
    const int s0 = blockIdx.y * 128;
    const int b  = blockIdx.z;
    const int e  = (langs[b] - 4) & 7;

    const int t    = threadIdx.x;
    const int lane = t & 63;
    const int w    = t >> 6;
    const int wr   = w >> 1, wc = w & 1;
    const int lm   = lane & 15;
    const int lq   = lane >> 4;
    const int lr   = lane >> 3;
    const int lcg  = (lane & 7) ^ lr;
    const int hsw  = lm & 7;

    f32x4 acc[4][4];
#pragma unroll
    for (int i = 0; i < 4; ++i)
#pragma unroll
        for (int j = 0; j < 4; ++j) acc[i][j] = (f32x4){0.f, 0.f, 0.f, 0.f};

    const size_t hbase = ((size_t)b * S_ + s0) * F_;
    const size_t wbase = ((size_t)e * D_ + d0) * F_;
    const u16* hg = H   + hbase + (size_t)(w * 32 + lr) * F_ + lcg * 8;
    const u16* wg = W2t + wbase + (size_t)(w * 32 + lr) * F_ + lcg * 8;

    for (int kt = 0; kt < F_ / 64; ++kt) {
        const int k0 = kt * 64;
        __syncthreads();
#pragma unroll
        for (int i = 0; i < 4; ++i)
            gload_lds16(hg + (size_t)i * 8 * F_ + k0, sH + (w * 32 + i * 8) * 64);
#pragma unroll
        for (int i = 0; i < 4; ++i)
            gload_lds16(wg + (size_t)i * 8 * F_ + k0, sW + (w * 32 + i * 8) * 64);
        __syncthreads();

#pragma unroll
        for (int kk = 0; kk < 64; kk += 32) {
            const int cgb = kk >> 3;
            short8 a[4], bb[4];
#pragma unroll
            for (int i = 0; i < 4; ++i) {
                const int r = wr * 64 + i * 16 + lm;
                a[i] = *(const short8*)(sH + r * 64 + (((cgb + lq) ^ hsw) << 3));
            }
#pragma unroll
            for (int j = 0; j < 4; ++j) {
                const int n = wc * 64 + j * 16 + lm;
                bb[j] = *(const short8*)(sW + n * 64 + (((cgb + lq) ^ hsw) << 3));
            }
#pragma unroll
            for (int i = 0; i < 4; ++i)
#pragma unroll
                for (int j = 0; j < 4; ++j)
                    acc[i][j] = __builtin_amdgcn_mfma_f32_16x16x32_bf16(a[i], bb[j], acc[i][j], 0, 0, 0);
        }
    }

#pragma unroll
    for (int i = 0; i < 4; ++i)
#pragma unroll
        for (int j = 0; j < 4; ++j)
#pragma unroll
            for (int r = 0; r < 4; ++r) {
                const int row = wr * 64 + i * 16 + lq * 4 + r;
                const int col = wc * 64 + j * 16 + lm;
                Y[((size_t)b * S_ + s0 + row) * D_ + d0 + col] = acc[i][j][r];
            }
}

// ===========================================================================
// Fallback path (R2 structure, f32 hard-coded) for small ws_size.
// ===========================================================================
__device__ __forceinline__ U16x8 load8f(const float* p, size_t off) {
    U16x8 r;
    const float4 v0 = *(const float4*)(p + off);
    const float4 v1 = *(const float4*)(p + off + 4);
    r.s[0] = f2b(v0.x); r.s[1] = f2b(v0.y); r.s[2] = f2b(v0.z); r.s[3] = f2b(v0.w);
    r.s[4] = f2b(v1.x); r.s[5] = f2b(v1.y); r.s[6] = f2b(v1.z); r.s[7] = f2b(v1.w);
    return r;
}

__global__ __launch_bounds__(256, 2)
void gateup_fb(const float* __restrict__ X, const float* __restrict__ W1,
               const float* __restrict__ W3, const int* __restrict__ langs,
               u16* __restrict__ H, int s_off, int schunk)
{
    __shared__ u16 sX [128 * 72];
    __shared__ u16 sW1[ 64 * 72];
    __shared__ u16 sW3[ 64 * 72];
    const int f0 = blockIdx.x * 64;
    const int sl = blockIdx.y * 128;
    const int b  = blockIdx.z;
    const int e  = (langs[b] - 4) & 7;
    const int t = threadIdx.x, lane = t & 63, w = t >> 6;
    const int wr = w >> 1, wc = w & 1, lm = lane & 15, lq = lane >> 4;
    const int wsel = t >> 7, idx = t & 127;
    const int wn = (idx & 7) * 8, wk = (idx >> 3) * 4;
    const float* Wsrc = wsel ? W3 : W1;
    u16* sWdst = wsel ? sW3 : sW1;

    f32x4 acc1[4][2], acc2[4][2];
#pragma unroll
    for (int i = 0; i < 4; ++i)
#pragma unroll
        for (int j = 0; j < 2; ++j) {
            acc1[i][j] = (f32x4){0.f,0.f,0.f,0.f};
            acc2[i][j] = (f32x4){0.f,0.f,0.f,0.f};
        }
    const size_t xbase = ((size_t)b * S_ + s_off + sl) * D_;
    const size_t wbase = (size_t)e * D_ * F_ + f0;
    for (int kt = 0; kt < D_ / 64; ++kt) {
        const int k0 = kt * 64;
        U16x8 xr[4], rr[4];
#pragma unroll
        for (int i = 0; i < 4; ++i) {
            const int ch = t + i * 256, row = ch >> 3, kk = (ch & 7) * 8;
            xr[i] = load8f(X, xbase + (size_t)row * D_ + k0 + kk);
        }
#pragma unroll
        for (int r = 0; r < 4; ++r)
            rr[r] = load8f(Wsrc, wbase + (size_t)(k0 + wk + r) * F_ + wn);
        __syncthreads();
#pragma unroll
        for (int i = 0; i < 4; ++i) {
            const int ch = t + i * 256, row = ch >> 3, kk = (ch & 7) * 8;
            *(uint4*)(sX + row * 72 + kk) = xr[i].v;
        }
#pragma unroll
        for (int j = 0; j < 8; ++j) {
            U16x4 o;
            o.s[0] = rr[0].s[j]; o.s[1] = rr[1].s[j];
            o.s[2] = rr[2].s[j]; o.s[3] = rr[3].s[j];
            *(uint2*)(sWdst + (wn + j) * 72 + wk) = o.v;
        }
        __syncthreads();
#pragma unroll
        for (int kk = 0; kk < 64; kk += 32) {
            short8 a[4], b1[2], b3[2];
#pragma unroll
            for (int i = 0; i < 4; ++i)
                a[i] = *(const short8*)(sX + (wr * 64 + i * 16 + lm) * 72 + kk + lq * 8);
#pragma unroll
            for (int j = 0; j < 2; ++j) {
                b1[j] = *(const short8*)(sW1 + (wc * 32 + j * 16 + lm) * 72 + kk + lq * 8);
                b3[j] = *(const short8*)(sW3 + (wc * 32 + j * 16 + lm) * 72 + kk + lq * 8);
            }
#pragma unroll
            for (int i = 0; i < 4; ++i)
#pragma unroll
                for (int j = 0; j < 2; ++j) {
                    acc1[i][j] = __builtin_amdgcn_mfma_f32_16x16x32_bf16(a[i], b1[j], acc1[i][j], 0, 0, 0);
                    acc2[i][j] = __builtin_amdgcn_mfma_f32_16x16x32_bf16(a[i], b3[j], acc2[i][j], 0, 0, 0);
                }
        }
    }
#pragma unroll
    for (int i = 0; i < 4; ++i)
#pragma unroll
        for (int j = 0; j < 2; ++j)
#pragma unroll
            for (int r = 0; r < 4; ++r) {
                const int row = wr * 64 + i * 16 + lq * 4 + r;
                const int col = wc * 32 + j * 16 + lm;
                H[((size_t)b * schunk + sl + row) * F_ + f0 + col] =
                    f2b(gelu_exact(acc1[i][j][r]) * acc2[i][j][r]);
            }
}

__global__ __launch_bounds__(256, 2)
void down_fb(const u16* __restrict__ Hm, const float* __restrict__ W2,
             const int* __restrict__ langs, float* __restrict__ Y,
             int s_off, int schunk)
{
    __shared__ u16 sH[128 * 72];
    __shared__ u16 sW[128 * 72];
    const int d0 = blockIdx.x * 128;
    const int sl = blockIdx.y * 128;
    const int b  = blockIdx.z;
    const int e  = (langs[b] - 4) & 7;
    const int t = threadIdx.x, lane = t & 63, w = t >> 6;
    const int wr = w >> 1, wc = w & 1, lm = lane & 15, lq = lane >> 4;
    const int wn = (t & 15) * 8, wk = (t >> 4) * 4;

    f32x4 acc[4][4];
#pragma unroll
    for (int i = 0; i < 4; ++i)
#pragma unroll
        for (int j = 0; j < 4; ++j) acc[i][j] = (f32x4){0.f,0.f,0.f,0.f};
    const size_t hbase = ((size_t)b * schunk + sl) * F_;
    const size_t wbase = (size_t)e * F_ * D_ + d0;
    for (int kt = 0; kt < F_ / 64; ++kt) {
        const int k0 = kt * 64;
        U16x8 hr[4], rr[4];
#pragma unroll
        for (int i = 0; i < 4; ++i) {
            const int ch = t + i * 256, row = ch >> 3, kk = (ch & 7) * 8;
            hr[i].v = *(const uint4*)(Hm + hbase + (size_t)row * F_ + k0 + kk);
        }
#pragma unroll
        for (int r = 0; r < 4; ++r)
            rr[r] = load8f(W2, wbase + (size_t)(k0 + wk + r) * D_ + wn);
        __syncthreads();
#pragma unroll
        for (int i = 0; i < 4; ++i) {
            const int ch = t + i * 256, row = ch >> 3, kk = (ch & 7) * 8;
            *(uint4*)(sH + row * 72 + kk) = hr[i].v;
        }
#pragma unroll
        for (int j = 0; j < 8; ++j) {
            U16x4 o;
            o.s[0] = rr[0].s[j]; o.s[1] = rr[1].s[j];
            o.s[2] = rr[2].s[j]; o.s[3] = rr[3].s[j];
            *(uint2*)(sW + (wn + j) * 72 + wk) = o.v;
        }
        __syncthreads();
#pragma unroll
        for (int kk = 0; kk < 64; kk += 32) {
            short8 a[4], bb[4];
#pragma unroll
            for (int i = 0; i < 4; ++i)
                a[i] = *(const short8*)(sH + (wr * 64 + i * 16 + lm) * 72 + kk + lq * 8);
#pragma unroll
            for (int j = 0; j < 4; ++j)
                bb[j] = *(const short8*)(sW + (wc * 64 + j * 16 + lm) * 72 + kk + lq * 8);
#pragma unroll
            for (int i = 0; i < 4; ++i)
#pragma unroll
                for (int j = 0; j < 4; ++j)
                    acc[i][j] = __builtin_amdgcn_mfma_f32_16x16x32_bf16(a[i], bb[j], acc[i][j], 0, 0, 0);
        }
    }
#pragma unroll
    for (int i = 0; i < 4; ++i)
#pragma unroll
        for (int j = 0; j < 4; ++j)
#pragma unroll
            for (int r = 0; r < 4; ++r) {
                const int row = wr * 64 + i * 16 + lq * 4 + r;
                const int col = wc * 64 + j * 16 + lm;
                Y[((size_t)b * S_ + s_off + sl + row) * D_ + d0 + col] = acc[i][j][r];
            }
}

extern "C" void kernel_launch(void* const* d_in, const int* in_sizes, int n_in,
                              void* d_out, int out_size, void* d_ws, size_t ws_size,
                              hipStream_t stream) {
    // dict order: hidden_states, w1, w2, w3, langs (w2 BEFORE w3)
    const float* X  = (const float*)d_in[0];
    const float* W1 = (const float*)d_in[1];
    const float* W2 = (const float*)d_in[2];
    const float* W3 = (const float*)d_in[3];
    const int* langs = (const int*)d_in[4];
    float* Y = (float*)d_out;

    const size_t szXb = (size_t)B_ * S_ * D_ * 2;   //  32 MiB
    const size_t szW  = (size_t)E_ * F_ * D_ * 2;   //  64 MiB
    const size_t szH  = (size_t)B_ * S_ * F_ * 2;   // 128 MiB
    const size_t need = szXb + 2 * szW + szH;       // 288 MiB

    if (ws_size >= need) {
        u16* Xb  = (u16*)d_ws;
        u16* W1t = (u16*)((char*)d_ws + szXb);
        u16* W3t = (u16*)((char*)d_ws + szXb + szW);
        u16* W2t = W1t;   // reused after gateup (stream-ordered)
        u16* Hb  = (u16*)((char*)d_ws + szXb + 2 * szW);

        convert_x<<<(B_ * S_ * D_) / (256 * 8), 256, 0, stream>>>(X, Xb);
        dim3 gt1(F_ / 64, D_ / 64, E_);
        transpose_w<<<gt1, 256, 0, stream>>>(W1, W1t, D_, F_);
        transpose_w<<<gt1, 256, 0, stream>>>(W3, W3t, D_, F_);
        dim3 g1(F_ / 64, S_ / 128, B_);
        gateup_v2<<<g1, 256, 0, stream>>>(Xb, W1t, W3t, langs, Hb);
        dim3 gt2(D_ / 64, F_ / 64, E_);
        transpose_w<<<gt2, 256, 0, stream>>>(W2, W2t, F_, D_);
        dim3 g2(D_ / 128, S_ / 128, B_);
        down_v2<<<g2, 256, 0, stream>>>(Hb, W2t, langs, Y);
    } else {
        u16* H = (u16*)d_ws;
        const size_t slab = (size_t)B_ * F_ * 2 * 128;
        int nslabs = (int)(ws_size / slab);
        if (nslabs < 1) nslabs = 1;
        if (nslabs > S_ / 128) nslabs = S_ / 128;
        const int SCH = nslabs * 128;
        for (int s0 = 0; s0 < S_; s0 += SCH) {
            const int rows = (S_ - s0 < SCH) ? (S_ - s0) : SCH;
            dim3 g1(F_ / 64, rows / 128, B_);
            gateup_fb<<<g1, 256, 0, stream>>>(X, W1, W3, langs, H, s0, SCH);
            dim3 g2(D_ / 128, rows / 128, B_);
            down_fb<<<g2, 256, 0, stream>>>(H, W2, langs, Y, s0, SCH);
        }
    }
}